// Round 14
// baseline (4330.901 us; speedup 1.0000x reference)
//
#include <hip/hip_runtime.h>
#include <stdint.h>

// out[b,o,m] = sum_i in[b,i,m] * w[i,o,m]  (complex, fp32)
// B=32, Ci=Co=128, M=64*65=4160. One float2 per complex element.
//
// R14: 128B-transaction staging. Model fitting R2-R13: chip VMEM ceiling
// ~50-65G transactions/s; MPB=8 staging = 64B/trans -> 3.2-4.2 TB/s
// plateau (R8/R9 measured at exactly this). MPB=16 -> every DMA segment =
// 128B aligned-contiguous (8 lanes x 16B) -> 2x bytes at the same rate.
// Geometry: 260 mt x 4 oj = 1040 jobs; block 32b x 32o x 16m, 512 thr,
// thread tile 4b x 4o x 2m. KC=2 (chunk 16KB), dbuf 32KB -> 4 independent
// blocks/CU (R9's slack structure). Uniform 2 gload_lds/thread/chunk,
// issued right after the top barrier (issue-to-wait = 1 period ~2us).
// A LDS reads: 8-way broadcast of one 128B row -> 0 conflicts, no swizzle.
// Tail (1040 = 1024+16): last 16 jobs split into 32 k-halves that
// atomicAdd onto a pre-zeroed output slice (zero kernel runs first on the
// stream; 0+a+b is order-independent -> deterministic).

typedef float f2 __attribute__((ext_vector_type(2)));
typedef float f4 __attribute__((ext_vector_type(4)));

#define NB 32
#define CI 128
#define CO 128
#define OT 32
#define MODES 4160
#define MPB 16
#define KC 2
#define ABUF_F2 (KC * NB * MPB)        // 1024 f2 = 8 KB
#define WBUF_F2 (KC * OT * MPB)        // 1024 f2 = 8 KB
#define BUF_F2  (ABUF_F2 + WBUF_F2)    // 16 KB per buffer

// acc.lo += a.lo*w.lo - a.hi*w.hi ; acc.hi += a.lo*w.hi + a.hi*w.lo
#define CFMA(acc, av, wv)                                                      \
  asm("v_pk_fma_f32 %0, %1, %2, %0 op_sel:[0,0,0] op_sel_hi:[0,1,1]"           \
      : "+v"(acc) : "v"(av), "v"(wv));                                         \
  asm("v_pk_fma_f32 %0, %1, %2, %0 op_sel:[1,1,0] op_sel_hi:[1,0,1] "          \
      "neg_lo:[1,0,0]"                                                         \
      : "+v"(acc) : "v"(av), "v"(wv));

#define VM_WAIT0 asm volatile("s_waitcnt vmcnt(0)" ::: "memory")

__device__ __forceinline__ void gload16(const f2* g, f2* l) {
    __builtin_amdgcn_global_load_lds(
        (const __attribute__((address_space(1))) uint32_t*)g,
        (__attribute__((address_space(3))) uint32_t*)l, 16, 0, 0);
}

// Stage one K-chunk (KC=2): 2 x 16B DMA per thread, ALL 128B-contiguous
// segments (8 consecutive lanes cover one (row,k) 128B mode-row).
// A unit t: kk=t>>8, b=(t>>3)&31, mo=t&7. LDS f2 slot = t*2 (linear).
// W unit t: kk=t>>8, o=(t>>3)&31, mo=t&7. LDS f2 slot = ABUF + t*2.
__device__ __forceinline__ void stage_chunk(const f2* __restrict__ Ig,
                                            const f2* __restrict__ Wl,
                                            f2* dst, int t, int m0,
                                            int obase, int kglob) {
    const int kk = t >> 8, row = (t >> 3) & 31, mo = t & 7;
    gload16(Ig + (size_t)(row * CI + kglob + kk) * MODES + m0 + mo * 2,
            dst + t * 2);
    gload16(Wl + (size_t)((kglob + kk) * CO + obase + row) * MODES + m0 + mo * 2,
            dst + ABUF_F2 + t * 2);
}

__global__ void zero_tail(f2* __restrict__ Og) {
    // zero modes [4096,4160) for all (b,o): the 16 tail jobs' output (2MB)
    const int tid = blockIdx.x * 256 + threadIdx.x;   // 262144 total
    const int mm = tid & 63;
    const int o  = (tid >> 6) & 127;
    const int b  = tid >> 13;
    Og[(size_t)(b * CO + o) * MODES + 4096 + mm] = (f2)(0.0f);
}

__global__ __launch_bounds__(512, 8)
void cmul2d_kernel(const f2* __restrict__ Ig,
                   const f2* __restrict__ Wl,
                   f2* __restrict__ Og) {
    __shared__ f2 lds[2 * BUF_F2];   // 32 KB -> 4 blocks/CU

    const int t   = threadIdx.x;
    const int bid = blockIdx.x;

    // bids 0..1023: full jobs (k 0..127). bids 1024..1055: 32 k-halves of
    // the last 16 jobs (jid 1024..1039), atomic epilogue.
    int jid, k0, nch;
    bool tail;
    if (bid < 1024) { jid = bid;               k0 = 0;                nch = 64; tail = false; }
    else { const int x = bid - 1024;
           jid = 1024 + (x & 15);              k0 = (x >> 4) * 64;    nch = 32; tail = true;  }

    const int m0    = (jid >> 2) * MPB;
    const int obase = (jid & 3) * OT;

    const int ml2 = t & 7;         // mode-pair lane (modes 2*ml2, 2*ml2+1)
    const int so  = (t >> 3) & 7;  // o-group (4 o each)
    const int sb  = t >> 6;        // b-group (4 b each) -- wave-uniform

    f2 acc[4][4][2];
#pragma unroll
    for (int r = 0; r < 4; ++r)
#pragma unroll
        for (int q = 0; q < 4; ++q) { acc[r][q][0] = (f2)(0.0f); acc[r][q][1] = (f2)(0.0f); }

    // prologue: stage chunk 0
    stage_chunk(Ig, Wl, lds, t, m0, obase, k0);

#pragma unroll 1
    for (int c = 0; c < nch; ++c) {
        VM_WAIT0;                           // chunk c's 2 DMAs landed
        __builtin_amdgcn_s_barrier();       // all waves: buf c ready, buf c+1 free
        __builtin_amdgcn_sched_barrier(0);

        const f2* Ab = lds + (c & 1) * BUF_F2;
        const f2* Wb = Ab + ABUF_F2;
        if (c + 1 < nch)                    // issue next chunk now; lands
            stage_chunk(Ig, Wl, lds + ((c + 1) & 1) * BUF_F2, t, m0, obase,
                        k0 + (c + 1) * KC); // under this chunk's compute

#pragma unroll
        for (int kk = 0; kk < KC; ++kk) {
            f4 a4[4], w4[4];
#pragma unroll
            for (int r = 0; r < 4; ++r)     // 8-way broadcast row: 0 conflicts
                a4[r] = *(const f4*)&Ab[kk * 512 + (sb * 4 + r) * MPB + ml2 * 2];
#pragma unroll
            for (int q = 0; q < 4; ++q)
                w4[q] = *(const f4*)&Wb[kk * 512 + (so * 4 + q) * MPB + ml2 * 2];
            __builtin_amdgcn_s_setprio(1);
#pragma unroll
            for (int r = 0; r < 4; ++r) {
                const f2 alo = __builtin_shufflevector(a4[r], a4[r], 0, 1);
                const f2 ahi = __builtin_shufflevector(a4[r], a4[r], 2, 3);
#pragma unroll
                for (int q = 0; q < 4; ++q) {
                    const f2 wlo = __builtin_shufflevector(w4[q], w4[q], 0, 1);
                    const f2 whi = __builtin_shufflevector(w4[q], w4[q], 2, 3);
                    CFMA(acc[r][q][0], alo, wlo);
                    CFMA(acc[r][q][1], ahi, whi);
                }
            }
            __builtin_amdgcn_s_setprio(0);
        }
    }

    // epilogue: per (b,o) one f4 store/add; 8 ml2 lanes = 128B contiguous
#pragma unroll
    for (int r = 0; r < 4; ++r) {
        const int b = sb * 4 + r;
#pragma unroll
        for (int q = 0; q < 4; ++q) {
            const int o = obase + so * 4 + q;
            const size_t pos = (size_t)(b * CO + o) * MODES + m0 + ml2 * 2;
            f4 v = { acc[r][q][0].x, acc[r][q][0].y,
                     acc[r][q][1].x, acc[r][q][1].y };
            if (!tail) {
                *(f4*)&Og[pos] = v;
            } else {
                float* p = (float*)&Og[pos];
                atomicAdd(p + 0, v.x); atomicAdd(p + 1, v.y);
                atomicAdd(p + 2, v.z); atomicAdd(p + 3, v.w);
            }
        }
    }
}

extern "C" void kernel_launch(void* const* d_in, const int* in_sizes, int n_in,
                              void* d_out, int out_size, void* d_ws, size_t ws_size,
                              hipStream_t stream) {
    const f2* I = (const f2*)d_in[0];
    const f2* W = (const f2*)d_in[1];
    f2* O = (f2*)d_out;
    zero_tail<<<1024, 256, 0, stream>>>(O);         // zero the 16 tail jobs
    cmul2d_kernel<<<1056, 512, 0, stream>>>(I, W, O); // 1024 full + 32 halves
}

// Round 15
// 258.052 us; speedup vs baseline: 16.7830x; 16.7830x over previous
//
#include <hip/hip_runtime.h>
#include <stdint.h>

// out[b,o,m] = sum_i in[b,i,m] * w[i,o,m]  (complex, fp32)
// B=32, Ci=Co=128, M=64*65=4160. One float2 per complex element.
//
// R15 = R14's 128B-transaction staging with the REAL bug fixed:
// R14 had __launch_bounds__(512,8) -> 64-VGPR cap -> 64-reg accumulator
// spilled to scratch -> 17.7GB HBM traffic, 4.3ms. Now (512,4) -> 128 cap,
// est ~115 used -> 2 blocks/CU (16 waves).
// Geometry: 260 mt x 4 oj = 1040 jobs; block 32b x 32o x 16modes, 512 thr,
// thread tile 4b x 4o x 2m (acc 32 f2 = 64 VGPR). KC=4: chunk 32KB,
// dbuf 64KB; 4 gload_lds dwordx4 per thread per chunk, every segment
// 128B aligned-contiguous (8 lanes x 16B). Stage issued right after the
// top barrier -> in flight for one full chunk-period (~2.4us).
// Tail (1040 = 1024+16): last 16 jobs as 32 k-halves that atomicAdd onto
// a pre-zeroed slice (zero kernel first on stream; deterministic).

typedef float f2 __attribute__((ext_vector_type(2)));
typedef float f4 __attribute__((ext_vector_type(4)));

#define NB 32
#define CI 128
#define CO 128
#define OT 32
#define MODES 4160
#define MPB 16
#define KC 4
#define NCHUNK (CI / KC)               // 32
#define ABUF_F2 (KC * NB * MPB)        // 2048 f2 = 16 KB
#define WBUF_F2 (KC * OT * MPB)        // 2048 f2 = 16 KB
#define BUF_F2  (ABUF_F2 + WBUF_F2)    // 32 KB per buffer

// acc.lo += a.lo*w.lo - a.hi*w.hi ; acc.hi += a.lo*w.hi + a.hi*w.lo
#define CFMA(acc, av, wv)                                                      \
  asm("v_pk_fma_f32 %0, %1, %2, %0 op_sel:[0,0,0] op_sel_hi:[0,1,1]"           \
      : "+v"(acc) : "v"(av), "v"(wv));                                         \
  asm("v_pk_fma_f32 %0, %1, %2, %0 op_sel:[1,1,0] op_sel_hi:[1,0,1] "          \
      "neg_lo:[1,0,0]"                                                         \
      : "+v"(acc) : "v"(av), "v"(wv));

#define VM_WAIT0 asm volatile("s_waitcnt vmcnt(0)" ::: "memory")

__device__ __forceinline__ void gload16(const f2* g, f2* l) {
    __builtin_amdgcn_global_load_lds(
        (const __attribute__((address_space(1))) uint32_t*)g,
        (__attribute__((address_space(3))) uint32_t*)l, 16, 0, 0);
}

// Stage one K-chunk (KC=4): 2048 16B units, 4 per thread (2 A + 2 W).
// A unit u (0..1023): u = kk*256 + b*8 + mu  -> LDS f2 slot u*2 (linear);
//   global: (b, k0+kk, m0 + mu*2). 8 consecutive u = one 128B mode-row.
// W unit v (0..1023): v = kk*256 + o*8 + mu  -> slot ABUF + v*2;
//   global: (k0+kk, obase+o, m0 + mu*2).
__device__ __forceinline__ void stage_chunk(const f2* __restrict__ Ig,
                                            const f2* __restrict__ Wl,
                                            f2* dst, int t, int m0,
                                            int obase, int k0) {
#pragma unroll
    for (int p = 0; p < 2; ++p) {
        const int u  = p * 512 + t;
        const int kk = u >> 8, row = (u >> 3) & 31, mu = u & 7;
        gload16(Ig + (size_t)(row * CI + k0 + kk) * MODES + m0 + mu * 2,
                dst + u * 2);
        gload16(Wl + (size_t)((k0 + kk) * CO + obase + row) * MODES + m0 + mu * 2,
                dst + ABUF_F2 + u * 2);
    }
}

__global__ void zero_tail(f2* __restrict__ Og) {
    // zero modes [4096,4160) for all (b,o): the 16 tail jobs' output (2MB)
    const int tid = blockIdx.x * 256 + threadIdx.x;   // 262144 total
    const int mm = tid & 63;
    const int o  = (tid >> 6) & 127;
    const int b  = tid >> 13;
    Og[(size_t)(b * CO + o) * MODES + 4096 + mm] = (f2)(0.0f);
}

__global__ __launch_bounds__(512, 4)
void cmul2d_kernel(const f2* __restrict__ Ig,
                   const f2* __restrict__ Wl,
                   f2* __restrict__ Og) {
    __shared__ f2 lds[2 * BUF_F2];   // 64 KB -> 2 blocks/CU

    const int t   = threadIdx.x;
    const int bid = blockIdx.x;

    // bids 0..1023: full jobs. bids 1024..1055: 32 k-halves of the last
    // 16 jobs (jid 1024..1039), atomic epilogue onto pre-zeroed output.
    int jid, k0, nch;
    bool tail;
    if (bid < 1024) { jid = bid;          k0 = 0;             nch = NCHUNK;     tail = false; }
    else { const int x = bid - 1024;
           jid = 1024 + (x & 15);         k0 = (x >> 4) * 64; nch = NCHUNK / 2; tail = true;  }

    const int m0    = (jid >> 2) * MPB;
    const int obase = (jid & 3) * OT;

    const int ml2 = t & 7;         // mode-pair lane (modes 2*ml2, 2*ml2+1)
    const int so  = (t >> 3) & 7;  // o-group (4 o each)
    const int sb  = t >> 6;        // b-group (4 b each) -- wave-uniform

    f2 acc[4][4][2];
#pragma unroll
    for (int r = 0; r < 4; ++r)
#pragma unroll
        for (int q = 0; q < 4; ++q) { acc[r][q][0] = (f2)(0.0f); acc[r][q][1] = (f2)(0.0f); }

    // prologue: stage chunk 0 into buffer 0
    stage_chunk(Ig, Wl, lds, t, m0, obase, k0);

#pragma unroll 1
    for (int c = 0; c < nch; ++c) {
        VM_WAIT0;                           // own chunk-c DMAs retired
        __builtin_amdgcn_s_barrier();       // all waves: buf c ready, other buf free
        __builtin_amdgcn_sched_barrier(0);

        const f2* Ab = lds + (c & 1) * BUF_F2;
        const f2* Wb = Ab + ABUF_F2;
        if (c + 1 < nch)                    // issue next chunk; in flight for
            stage_chunk(Ig, Wl, lds + ((c + 1) & 1) * BUF_F2, t, m0, obase,
                        k0 + (c + 1) * KC); // one full chunk-period
        __builtin_amdgcn_sched_barrier(0);

#pragma unroll
        for (int kk = 0; kk < KC; ++kk) {
            f4 a4[4], w4[4];
#pragma unroll
            for (int r = 0; r < 4; ++r)     // broadcast row: conflict-free
                a4[r] = *(const f4*)&Ab[kk * (NB * MPB) + (sb * 4 + r) * MPB + ml2 * 2];
#pragma unroll
            for (int q = 0; q < 4; ++q)     // 2 rows/bank-group: 2-way, free
                w4[q] = *(const f4*)&Wb[kk * (OT * MPB) + (so * 4 + q) * MPB + ml2 * 2];
            __builtin_amdgcn_s_setprio(1);
#pragma unroll
            for (int r = 0; r < 4; ++r) {
                const f2 alo = __builtin_shufflevector(a4[r], a4[r], 0, 1);
                const f2 ahi = __builtin_shufflevector(a4[r], a4[r], 2, 3);
#pragma unroll
                for (int q = 0; q < 4; ++q) {
                    const f2 wlo = __builtin_shufflevector(w4[q], w4[q], 0, 1);
                    const f2 whi = __builtin_shufflevector(w4[q], w4[q], 2, 3);
                    CFMA(acc[r][q][0], alo, wlo);
                    CFMA(acc[r][q][1], ahi, whi);
                }
            }
            __builtin_amdgcn_s_setprio(0);
        }
    }

    // epilogue: per (b,o) one 16B op; 8 ml2 lanes = 128B contiguous
#pragma unroll
    for (int r = 0; r < 4; ++r) {
        const int b = sb * 4 + r;
#pragma unroll
        for (int q = 0; q < 4; ++q) {
            const int o = obase + so * 4 + q;
            const size_t pos = (size_t)(b * CO + o) * MODES + m0 + ml2 * 2;
            f4 v = { acc[r][q][0].x, acc[r][q][0].y,
                     acc[r][q][1].x, acc[r][q][1].y };
            if (!tail) {
                *(f4*)&Og[pos] = v;
            } else {
                float* p = (float*)&Og[pos];
                atomicAdd(p + 0, v.x); atomicAdd(p + 1, v.y);
                atomicAdd(p + 2, v.z); atomicAdd(p + 3, v.w);
            }
        }
    }
}

extern "C" void kernel_launch(void* const* d_in, const int* in_sizes, int n_in,
                              void* d_out, int out_size, void* d_ws, size_t ws_size,
                              hipStream_t stream) {
    const f2* I = (const f2*)d_in[0];
    const f2* W = (const f2*)d_in[1];
    f2* O = (f2*)d_out;
    zero_tail<<<1024, 256, 0, stream>>>(O);           // zero the 16 tail jobs
    cmul2d_kernel<<<1056, 512, 0, stream>>>(I, W, O); // 1024 full + 32 halves
}